// Round 4
// baseline (773.007 us; speedup 1.0000x reference)
//
#include <hip/hip_runtime.h>
#include <hip/hip_bf16.h>

#define N_NODES  50000
#define N_GRAPHS 128
#define N_EDGES  800000
#define HID      128
#define SCAN_BS  256
#define SCAN_NB  ((N_NODES + SCAN_BS - 1) / SCAN_BS)

typedef __attribute__((ext_vector_type(8))) short short8;
typedef __attribute__((ext_vector_type(4))) float f32x4;

static __device__ __forceinline__ ushort f2bf(float f){
  __hip_bfloat16 h = __float2bfloat16(f);
  return *reinterpret_cast<ushort*>(&h);
}
static __device__ __forceinline__ float bf_lo(uint pk){ return __uint_as_float(pk << 16); }
static __device__ __forceinline__ float bf_hi(uint pk){ return __uint_as_float(pk & 0xffff0000u); }

// ---------------- graph preprocessing ----------------

__global__ void k_count(const int* __restrict__ dst, int* __restrict__ deg, int E){
  int i = blockIdx.x*blockDim.x + threadIdx.x;
  if (i < E) atomicAdd(&deg[dst[i]], 1);
}

__global__ void k_scan1(const int* __restrict__ deg, int* __restrict__ lexc,
                        int* __restrict__ bsum, float* __restrict__ dinv, int N){
  __shared__ int s[SCAN_BS];
  int t = threadIdx.x, i = blockIdx.x*SCAN_BS + t;
  int v = (i < N) ? deg[i] : 0;
  if (i < N) dinv[i] = rsqrtf((float)(v + 1));   // +1 self loop
  s[t] = v;
  __syncthreads();
  int acc = v;
  for (int d = 1; d < SCAN_BS; d <<= 1){
    int u = (t >= d) ? s[t-d] : 0;
    __syncthreads();
    acc += u; s[t] = acc;
    __syncthreads();
  }
  if (i < N) lexc[i] = acc - v;
  if (t == SCAN_BS-1) bsum[blockIdx.x] = acc;
}

__global__ void k_scan2(const int* __restrict__ bsum, int* __restrict__ boff,
                        int* __restrict__ row_start){
  __shared__ int s[SCAN_NB];
  int t = threadIdx.x;
  int v = (t < SCAN_NB) ? bsum[t] : 0;
  if (t < SCAN_NB) s[t] = v;
  __syncthreads();
  int acc = v;
  for (int d = 1; d < SCAN_NB; d <<= 1){
    int u = (t >= d && t - d < SCAN_NB) ? s[t-d] : 0;
    __syncthreads();
    if (t < SCAN_NB){ acc += u; s[t] = acc; }
    __syncthreads();
  }
  if (t < SCAN_NB) boff[t] = acc - v;
  if (t == SCAN_NB-1) row_start[N_NODES] = acc;
}

__global__ void k_scan3(const int* __restrict__ lexc, const int* __restrict__ boff,
                        int* __restrict__ row_start, int N){
  int i = blockIdx.x*blockDim.x + threadIdx.x;
  if (i < N) row_start[i] = lexc[i] + boff[i >> 8];
}

__global__ void k_scatter(const int* __restrict__ src, const int* __restrict__ dst,
                          const int* __restrict__ row_start, int* __restrict__ cursor,
                          int* __restrict__ csr_src, int E){
  int i = blockIdx.x*blockDim.x + threadIdx.x;
  if (i >= E) return;
  int d = dst[i];
  int pos = row_start[d] + atomicAdd(&cursor[d], 1);
  csr_src[pos] = src[i];
}

// transpose + bf16-convert the three weight matrices in one launch
__global__ void k_wt3(const float* __restrict__ W0, ushort* __restrict__ T0,
                      const float* __restrict__ W1, ushort* __restrict__ T1,
                      const float* __restrict__ W2, ushort* __restrict__ T2){
  int idx = blockIdx.x*blockDim.x + threadIdx.x;
  if (idx < 768*HID){
    int k = idx >> 7, n = idx & 127;
    T0[n*768 + k] = f2bf(W0[idx]);
  } else if (idx < 768*HID + HID*HID){
    int j = idx - 768*HID; int k = j >> 7, n = j & 127;
    T1[n*HID + k] = f2bf(W1[j]);
  } else if (idx < 768*HID + 2*HID*HID){
    int j = idx - 768*HID - HID*HID; int k = j >> 7, n = j & 127;
    T2[n*HID + k] = f2bf(W2[j]);
  }
}

// ---------------- bf16 MFMA GEMM: Out[M][128] = A[M][K] @ W[K][128] ----------------

template<int K, bool A_F32, bool OUT_BF16, bool BIAS, bool SCALE>
__global__ __launch_bounds__(256) void k_gemm(const void* __restrict__ Aptr,
                                              const ushort* __restrict__ Wt,
                                              const float* __restrict__ bias,
                                              const float* __restrict__ rowscale,
                                              void* __restrict__ Outp, int M){
  __shared__ __align__(16) ushort lA[64*32];    // [row][k]
  __shared__ __align__(16) ushort lB[128*32];   // [n][k]
  int tid  = threadIdx.x;
  int wave = tid >> 6, lane = tid & 63;
  int kg   = lane >> 4, lr = lane & 15;
  int m0   = blockIdx.x * 64;

  f32x4 acc[8];
  #pragma unroll
  for (int i = 0; i < 8; i++) acc[i] = f32x4{0.f, 0.f, 0.f, 0.f};

  for (int k0 = 0; k0 < K; k0 += 32){
    if (A_F32){
      const float* A = (const float*)Aptr;
      #pragma unroll
      for (int i = 0; i < 2; i++){
        int l = tid + i*256;
        int r = l >> 3, c4 = (l & 7) * 4;
        int gm = m0 + r;
        float4 v = make_float4(0.f, 0.f, 0.f, 0.f);
        if (gm < M) v = *(const float4*)(A + (size_t)gm*K + k0 + c4);
        ushort4 u; u.x = f2bf(v.x); u.y = f2bf(v.y); u.z = f2bf(v.z); u.w = f2bf(v.w);
        *(ushort4*)&lA[r*32 + c4] = u;
      }
    } else {
      const ushort* A = (const ushort*)Aptr;
      int r = tid >> 2, c8 = (tid & 3) * 8;
      int gm = m0 + r;
      int4 v = make_int4(0, 0, 0, 0);
      if (gm < M) v = *(const int4*)(A + (size_t)gm*K + k0 + c8);
      *(int4*)&lA[r*32 + c8] = v;
    }
    #pragma unroll
    for (int i = 0; i < 2; i++){
      int l = tid + i*256;
      int n = l >> 2, c8 = (l & 3) * 8;
      *(int4*)&lB[n*32 + c8] = *(const int4*)(Wt + (size_t)n*K + k0 + c8);
    }
    __syncthreads();

    short8 a = *(const short8*)&lA[(wave*16 + lr)*32 + kg*8];
    #pragma unroll
    for (int nt = 0; nt < 8; nt++){
      short8 b = *(const short8*)&lB[(nt*16 + lr)*32 + kg*8];
      acc[nt] = __builtin_amdgcn_mfma_f32_16x16x32_bf16(a, b, acc[nt], 0, 0, 0);
    }
    __syncthreads();
  }

  #pragma unroll
  for (int nt = 0; nt < 8; nt++){
    #pragma unroll
    for (int r = 0; r < 4; r++){
      int gm = m0 + wave*16 + kg*4 + r;
      int n  = nt*16 + lr;
      if (gm < M){
        float v = acc[nt][r];
        if (BIAS)  v += bias[n];
        if (SCALE) v *= rowscale[gm];
        if (OUT_BF16) ((ushort*)Outp)[(size_t)gm*HID + n] = f2bf(v);
        else          ((float*)Outp)[(size_t)gm*HID + n] = v;
      }
    }
  }
}

// ---------------- edge aggregation (dwordx4 gathers, 4 edges/instruction) ----------------
// Empirical law from rounds 0/1/3: k_agg time ~ (gather instructions) x 50-130 cyc,
// independent of bytes or L2 locality. So: maximize bytes per gather instruction.
// hw rows are 256 B (64 uints, packed bf16x2). Wave = 4 nodes; group q (16 lanes)
// owns node q; lane p loads uint4 = row bytes [p*16, p*16+16) -> one wave instruction
// gathers 4 edges' FULL rows (1024 B). Per 16-edge stage: two 8-deep gather bursts
// (8 outstanding dwordx4). Edge index broadcast within a group via ds_swizzle
// BitMode src = (lane&0x10)|t (verified round 3). No cross-group reduction: lane p
// of group q finishes cols [8p..8p+7] of node q. Masked slots gather row 0 (cache-
// hot), contribution zeroed via mask-FMA.

#define AGG_G(U, t) { \
    int s_##U = __builtin_amdgcn_ds_swizzle(sl, ((t) << 5) | 0x10); \
    v[U] = hw4[(uint)s_##U*16u + (uint)p]; }

#define AGG_ACC(U, t) { \
    float mk = (r + (t) < deg) ? 1.0f : 0.0f; \
    ax0 += mk*bf_lo(v[U].x); ay0 += mk*bf_hi(v[U].x); \
    ax1 += mk*bf_lo(v[U].y); ay1 += mk*bf_hi(v[U].y); \
    ax2 += mk*bf_lo(v[U].z); ay2 += mk*bf_hi(v[U].z); \
    ax3 += mk*bf_lo(v[U].w); ay3 += mk*bf_hi(v[U].w); }

template<bool RELU, bool FUSE_POOL>
__global__ __launch_bounds__(256, 4) void k_agg(const uint4* __restrict__ hw4,
                                                const int* __restrict__ row_start,
                                                const int* __restrict__ csr_src,
                                                const float* __restrict__ dinv,
                                                const float* __restrict__ bias,
                                                uint4* __restrict__ OutBf,
                                                const int* __restrict__ batch,
                                                const int* __restrict__ gstart,
                                                float* __restrict__ g){
  int wave = threadIdx.x >> 6, lane = threadIdx.x & 63;
  int p = lane & 15, q = lane >> 4;
  int node = blockIdx.x*16 + wave*4 + q;     // grid = 3125 blocks exactly

  int b0 = row_start[node], e0 = row_start[node+1];
  int deg = e0 - b0;
  int dmax = max(deg, __shfl_xor(deg, 16));  // max degree over the wave's 4 nodes
  dmax = max(dmax, __shfl_xor(dmax, 32));

  uint4 s0 = hw4[(size_t)node*16 + p];       // self loop (pre-scaled by dinv[node])
  float ax0 = bf_lo(s0.x), ay0 = bf_hi(s0.x);
  float ax1 = bf_lo(s0.y), ay1 = bf_hi(s0.y);
  float ax2 = bf_lo(s0.z), ay2 = bf_hi(s0.z);
  float ax3 = bf_lo(s0.w), ay3 = bf_hi(s0.w);

  for (int r = 0; r < dmax; r += 16){
    int t16 = r + p;
    // each group stages its own node's next 16 edge indices (replicated in group lanes)
    int sl = (t16 < deg) ? __builtin_nontemporal_load(csr_src + b0 + t16) : 0;
    {
      uint4 v[8];
      AGG_G(0,0) AGG_G(1,1) AGG_G(2,2) AGG_G(3,3)
      AGG_G(4,4) AGG_G(5,5) AGG_G(6,6) AGG_G(7,7)
      AGG_ACC(0,0) AGG_ACC(1,1) AGG_ACC(2,2) AGG_ACC(3,3)
      AGG_ACC(4,4) AGG_ACC(5,5) AGG_ACC(6,6) AGG_ACC(7,7)
    }
    if (r + 8 < dmax){                       // wave-uniform (dmax uniform)
      uint4 v[8];
      AGG_G(0,8)  AGG_G(1,9)  AGG_G(2,10) AGG_G(3,11)
      AGG_G(4,12) AGG_G(5,13) AGG_G(6,14) AGG_G(7,15)
      AGG_ACC(0,8)  AGG_ACC(1,9)  AGG_ACC(2,10) AGG_ACC(3,11)
      AGG_ACC(4,12) AGG_ACC(5,13) AGG_ACC(6,14) AGG_ACC(7,15)
    }
  }

  float dd = dinv[node];
  const float4* b4 = (const float4*)bias;
  float4 bA = b4[2*p], bB = b4[2*p + 1];     // bias cols [8p..8p+7]
  float vx0 = ax0*dd + bA.x, vy0 = ay0*dd + bA.y;
  float vx1 = ax1*dd + bA.z, vy1 = ay1*dd + bA.w;
  float vx2 = ax2*dd + bB.x, vy2 = ay2*dd + bB.y;
  float vx3 = ax3*dd + bB.z, vy3 = ay3*dd + bB.w;
  if (RELU){
    vx0 = fmaxf(vx0, 0.f); vy0 = fmaxf(vy0, 0.f);
    vx1 = fmaxf(vx1, 0.f); vy1 = fmaxf(vy1, 0.f);
    vx2 = fmaxf(vx2, 0.f); vy2 = fmaxf(vy2, 0.f);
    vx3 = fmaxf(vx3, 0.f); vy3 = fmaxf(vy3, 0.f);
  }

  if (FUSE_POOL){
    int bg = batch[node];
    float cnt = (float)(gstart[bg+1] - gstart[bg]);
    float sc = 1.0f / fmaxf(cnt, 1.0f);
    float* gp = &g[bg*HID + 8*p];
    atomicAdd(gp + 0, vx0*sc); atomicAdd(gp + 1, vy0*sc);
    atomicAdd(gp + 2, vx1*sc); atomicAdd(gp + 3, vy1*sc);
    atomicAdd(gp + 4, vx2*sc); atomicAdd(gp + 5, vy2*sc);
    atomicAdd(gp + 6, vx3*sc); atomicAdd(gp + 7, vy3*sc);
  } else {
    uint4 pk;
    pk.x = (uint)f2bf(vx0) | ((uint)f2bf(vy0) << 16);
    pk.y = (uint)f2bf(vx1) | ((uint)f2bf(vy1) << 16);
    pk.z = (uint)f2bf(vx2) | ((uint)f2bf(vy2) << 16);
    pk.w = (uint)f2bf(vx3) | ((uint)f2bf(vy3) << 16);
    OutBf[(size_t)node*16 + p] = pk;         // row layout for next GEMM
  }
}

// ---------------- head ----------------

__global__ void k_ranges(const int* __restrict__ batch, int* __restrict__ gstart, int N, int G){
  int b = blockIdx.x*blockDim.x + threadIdx.x;
  if (b > G) return;
  int lo = 0, hi = N;
  while (lo < hi){ int mid = (lo + hi) >> 1; if (batch[mid] < b) lo = mid + 1; else hi = mid; }
  gstart[b] = lo;
}

__global__ void k_head(const float* __restrict__ g, const float* __restrict__ W1,
                       const float* __restrict__ b1, const float* __restrict__ W2,
                       const float* __restrict__ b2, float* __restrict__ out){
  __shared__ float row[128];
  __shared__ float z[128];
  int b = blockIdx.x, t = threadIdx.x;
  row[t] = g[b*HID + t];
  __syncthreads();
  float a = b1[t];
  #pragma unroll 8
  for (int k = 0; k < 128; k++) a += row[k] * W1[k*128 + t];
  z[t] = fmaxf(a, 0.f);
  __syncthreads();
  if (t < 3){
    float o = b2[t];
    #pragma unroll 8
    for (int k = 0; k < 128; k++) o += z[k] * W2[k*3 + t];
    out[b*3 + t] = o;
  }
}

// ---------------- launch ----------------

extern "C" void kernel_launch(void* const* d_in, const int* in_sizes, int n_in,
                              void* d_out, int out_size, void* d_ws, size_t ws_size,
                              hipStream_t stream) {
  const float* x     = (const float*)d_in[0];
  const int*   ei    = (const int*)  d_in[1];
  const int*   batch = (const int*)  d_in[2];
  const float* W_emb = (const float*)d_in[3];
  const float* b_emb = (const float*)d_in[4];
  const float* W_c1  = (const float*)d_in[5];
  const float* b_c1  = (const float*)d_in[6];
  const float* W_c2  = (const float*)d_in[7];
  const float* b_c2  = (const float*)d_in[8];
  const float* W_l1  = (const float*)d_in[9];
  const float* b_l1  = (const float*)d_in[10];
  const float* W_l2  = (const float*)d_in[11];
  const float* b_l2  = (const float*)d_in[12];
  const int* src = ei;
  const int* dst = ei + N_EDGES;
  float* out = (float*)d_out;

  char* ws = (char*)d_ws;
  size_t off = 0;
  auto alloc = [&](size_t n) -> char* {
    off = (off + 255) & ~(size_t)255;
    char* p = ws + off; off += n; return p;
  };
  int*    deg       = (int*)   alloc((size_t)N_NODES*4);
  int*    cursor    = (int*)   alloc((size_t)N_NODES*4);
  int*    row_start = (int*)   alloc((size_t)(N_NODES+1)*4);
  float*  dinv      = (float*) alloc((size_t)N_NODES*4);
  int*    lexc      = (int*)   alloc((size_t)N_NODES*4);
  int*    bsum      = (int*)   alloc((size_t)SCAN_NB*4);
  int*    boff      = (int*)   alloc((size_t)SCAN_NB*4);
  int*    csr_src   = (int*)   alloc((size_t)N_EDGES*4);
  ushort* wt_emb    = (ushort*)alloc((size_t)768*HID*2);
  ushort* wt_c1     = (ushort*)alloc((size_t)HID*HID*2);
  ushort* wt_c2     = (ushort*)alloc((size_t)HID*HID*2);
  ushort* t1        = (ushort*)alloc((size_t)N_NODES*HID*2);
  ushort* h2        = (ushort*)alloc((size_t)N_NODES*HID*2);
  uint*   hw        = (uint*)  alloc((size_t)N_NODES*64*4);   // packed bf16 x2, row layout
  float*  g         = (float*) alloc((size_t)N_GRAPHS*HID*4);
  int*    gstart    = (int*)   alloc((size_t)(N_GRAPHS+1)*4);

  hipMemsetAsync(deg,    0, (size_t)N_NODES*4, stream);
  hipMemsetAsync(cursor, 0, (size_t)N_NODES*4, stream);
  hipMemsetAsync(g,      0, (size_t)N_GRAPHS*HID*4, stream);

  int eb = (N_EDGES + 255) / 256;
  int nb = (N_NODES + 255) / 256;
  k_count  <<<eb, 256, 0, stream>>>(dst, deg, N_EDGES);
  k_scan1  <<<SCAN_NB, SCAN_BS, 0, stream>>>(deg, lexc, bsum, dinv, N_NODES);
  k_scan2  <<<1, 256, 0, stream>>>(bsum, boff, row_start);
  k_scan3  <<<nb, 256, 0, stream>>>(lexc, boff, row_start, N_NODES);
  k_scatter<<<eb, 256, 0, stream>>>(src, dst, row_start, cursor, csr_src, N_EDGES);
  k_ranges <<<1, 256, 0, stream>>>(batch, gstart, N_NODES, N_GRAPHS);

  k_wt3<<<(768*HID + 2*HID*HID + 255)/256, 256, 0, stream>>>(W_emb, wt_emb, W_c1, wt_c1, W_c2, wt_c2);

  int gemm_blocks = (N_NODES + 63) / 64;
  int agg_blocks  = N_NODES / 16;           // 3125, 16 nodes per block
  // t1 = x @ W_emb + b_emb (bf16)
  k_gemm<768, true,  true,  true,  false><<<gemm_blocks, 256, 0, stream>>>(x,  wt_emb, b_emb, nullptr, t1, N_NODES);
  // hw = (t1 @ W_c1) * dinv[row]  (packed bf16)
  k_gemm<128, false, true,  false, true ><<<gemm_blocks, 256, 0, stream>>>(t1, wt_c1, nullptr, dinv, hw, N_NODES);
  // h2 = relu(agg(hw) + b_c1) (bf16)
  k_agg<true,  false><<<agg_blocks, 256, 0, stream>>>((const uint4*)hw, row_start, csr_src, dinv, b_c1,
                                                      (uint4*)h2, nullptr, nullptr, nullptr);
  // hw = (h2 @ W_c2) * dinv[row] (packed bf16)
  k_gemm<128, false, true,  false, true ><<<gemm_blocks, 256, 0, stream>>>(h2, wt_c2, nullptr, dinv, hw, N_NODES);
  // g += pooled(agg(hw) + b_c2)   (fused)
  k_agg<false, true ><<<agg_blocks, 256, 0, stream>>>((const uint4*)hw, row_start, csr_src, dinv, b_c2,
                                                      nullptr, batch, gstart, g);

  k_head<<<N_GRAPHS, 128, 0, stream>>>(g, W_l1, b_l1, W_l2, b_l2, out);
}

// Round 5
// 468.982 us; speedup vs baseline: 1.6483x; 1.6483x over previous
//
#include <hip/hip_runtime.h>
#include <hip/hip_bf16.h>

#define N_NODES  50000
#define N_GRAPHS 128
#define N_EDGES  800000
#define HID      128
#define SCAN_BS  256
#define SCAN_NB  ((N_NODES + SCAN_BS - 1) / SCAN_BS)

typedef __attribute__((ext_vector_type(8))) short short8;
typedef __attribute__((ext_vector_type(4))) float f32x4;

static __device__ __forceinline__ ushort f2bf(float f){
  __hip_bfloat16 h = __float2bfloat16(f);
  return *reinterpret_cast<ushort*>(&h);
}
static __device__ __forceinline__ float bf_lo(uint pk){ return __uint_as_float(pk << 16); }
static __device__ __forceinline__ float bf_hi(uint pk){ return __uint_as_float(pk & 0xffff0000u); }

// ---------------- graph preprocessing ----------------

__global__ void k_count(const int* __restrict__ dst, int* __restrict__ deg, int E){
  int i = blockIdx.x*blockDim.x + threadIdx.x;
  if (i < E) atomicAdd(&deg[dst[i]], 1);
}

__global__ void k_scan1(const int* __restrict__ deg, int* __restrict__ lexc,
                        int* __restrict__ bsum, float* __restrict__ dinv, int N){
  __shared__ int s[SCAN_BS];
  int t = threadIdx.x, i = blockIdx.x*SCAN_BS + t;
  int v = (i < N) ? deg[i] : 0;
  if (i < N) dinv[i] = rsqrtf((float)(v + 1));   // +1 self loop
  s[t] = v;
  __syncthreads();
  int acc = v;
  for (int d = 1; d < SCAN_BS; d <<= 1){
    int u = (t >= d) ? s[t-d] : 0;
    __syncthreads();
    acc += u; s[t] = acc;
    __syncthreads();
  }
  if (i < N) lexc[i] = acc - v;
  if (t == SCAN_BS-1) bsum[blockIdx.x] = acc;
}

__global__ void k_scan2(const int* __restrict__ bsum, int* __restrict__ boff,
                        int* __restrict__ row_start){
  __shared__ int s[SCAN_NB];
  int t = threadIdx.x;
  int v = (t < SCAN_NB) ? bsum[t] : 0;
  if (t < SCAN_NB) s[t] = v;
  __syncthreads();
  int acc = v;
  for (int d = 1; d < SCAN_NB; d <<= 1){
    int u = (t >= d && t - d < SCAN_NB) ? s[t-d] : 0;
    __syncthreads();
    if (t < SCAN_NB){ acc += u; s[t] = acc; }
    __syncthreads();
  }
  if (t < SCAN_NB) boff[t] = acc - v;
  if (t == SCAN_NB-1) row_start[N_NODES] = acc;
}

__global__ void k_scan3(const int* __restrict__ lexc, const int* __restrict__ boff,
                        int* __restrict__ row_start, int N){
  int i = blockIdx.x*blockDim.x + threadIdx.x;
  if (i < N) row_start[i] = lexc[i] + boff[i >> 8];
}

__global__ void k_scatter(const int* __restrict__ src, const int* __restrict__ dst,
                          const int* __restrict__ row_start, int* __restrict__ cursor,
                          int* __restrict__ csr_src, int E){
  int i = blockIdx.x*blockDim.x + threadIdx.x;
  if (i >= E) return;
  int d = dst[i];
  int pos = row_start[d] + atomicAdd(&cursor[d], 1);
  csr_src[pos] = src[i];
}

// transpose + bf16-convert the three weight matrices in one launch
__global__ void k_wt3(const float* __restrict__ W0, ushort* __restrict__ T0,
                      const float* __restrict__ W1, ushort* __restrict__ T1,
                      const float* __restrict__ W2, ushort* __restrict__ T2){
  int idx = blockIdx.x*blockDim.x + threadIdx.x;
  if (idx < 768*HID){
    int k = idx >> 7, n = idx & 127;
    T0[n*768 + k] = f2bf(W0[idx]);
  } else if (idx < 768*HID + HID*HID){
    int j = idx - 768*HID; int k = j >> 7, n = j & 127;
    T1[n*HID + k] = f2bf(W1[j]);
  } else if (idx < 768*HID + 2*HID*HID){
    int j = idx - 768*HID - HID*HID; int k = j >> 7, n = j & 127;
    T2[n*HID + k] = f2bf(W2[j]);
  }
}

// ---------------- bf16 MFMA GEMM: Out[M][128] = A[M][K] @ W[K][128] ----------------

template<int K, bool A_F32, bool OUT_BF16, bool BIAS, bool SCALE>
__global__ __launch_bounds__(256) void k_gemm(const void* __restrict__ Aptr,
                                              const ushort* __restrict__ Wt,
                                              const float* __restrict__ bias,
                                              const float* __restrict__ rowscale,
                                              void* __restrict__ Outp, int M){
  __shared__ __align__(16) ushort lA[64*32];    // [row][k]
  __shared__ __align__(16) ushort lB[128*32];   // [n][k]
  int tid  = threadIdx.x;
  int wave = tid >> 6, lane = tid & 63;
  int kg   = lane >> 4, lr = lane & 15;
  int m0   = blockIdx.x * 64;

  f32x4 acc[8];
  #pragma unroll
  for (int i = 0; i < 8; i++) acc[i] = f32x4{0.f, 0.f, 0.f, 0.f};

  for (int k0 = 0; k0 < K; k0 += 32){
    if (A_F32){
      const float* A = (const float*)Aptr;
      #pragma unroll
      for (int i = 0; i < 2; i++){
        int l = tid + i*256;
        int r = l >> 3, c4 = (l & 7) * 4;
        int gm = m0 + r;
        float4 v = make_float4(0.f, 0.f, 0.f, 0.f);
        if (gm < M) v = *(const float4*)(A + (size_t)gm*K + k0 + c4);
        ushort4 u; u.x = f2bf(v.x); u.y = f2bf(v.y); u.z = f2bf(v.z); u.w = f2bf(v.w);
        *(ushort4*)&lA[r*32 + c4] = u;
      }
    } else {
      const ushort* A = (const ushort*)Aptr;
      int r = tid >> 2, c8 = (tid & 3) * 8;
      int gm = m0 + r;
      int4 v = make_int4(0, 0, 0, 0);
      if (gm < M) v = *(const int4*)(A + (size_t)gm*K + k0 + c8);
      *(int4*)&lA[r*32 + c8] = v;
    }
    #pragma unroll
    for (int i = 0; i < 2; i++){
      int l = tid + i*256;
      int n = l >> 2, c8 = (l & 3) * 8;
      *(int4*)&lB[n*32 + c8] = *(const int4*)(Wt + (size_t)n*K + k0 + c8);
    }
    __syncthreads();

    short8 a = *(const short8*)&lA[(wave*16 + lr)*32 + kg*8];
    #pragma unroll
    for (int nt = 0; nt < 8; nt++){
      short8 b = *(const short8*)&lB[(nt*16 + lr)*32 + kg*8];
      acc[nt] = __builtin_amdgcn_mfma_f32_16x16x32_bf16(a, b, acc[nt], 0, 0, 0);
    }
    __syncthreads();
  }

  #pragma unroll
  for (int nt = 0; nt < 8; nt++){
    #pragma unroll
    for (int r = 0; r < 4; r++){
      int gm = m0 + wave*16 + kg*4 + r;
      int n  = nt*16 + lr;
      if (gm < M){
        float v = acc[nt][r];
        if (BIAS)  v += bias[n];
        if (SCALE) v *= rowscale[gm];
        if (OUT_BF16) ((ushort*)Outp)[(size_t)gm*HID + n] = f2bf(v);
        else          ((float*)Outp)[(size_t)gm*HID + n] = v;
      }
    }
  }
}

// ---------------- edge aggregation (dwordx4 gathers, 4 edges/instruction) ----------------
// Wave = 4 nodes; group q (16 lanes) owns node q; lane p loads uint4 = row bytes
// [p*16, p*16+16) -> one wave instruction gathers 4 edges' FULL 256B rows (1 KB,
// zero overfetch). Per 16-edge stage: two 8-deep bursts; sched_barrier(0) between
// the 8 loads and the 8 accumulates forces all 8 to stay in flight (round 4: the
// compiler interleaved load->use, VGPR_Count=40, ILP ~1-2). Edge index broadcast
// within a group via ds_swizzle BitMode src=(lane&0x10)|t. Masked slots gather
// row 0 (cache-hot), contribution zeroed via mask-FMA. NO pooling fusion: round-4
// counters showed scattered f32 atomics = 1.6M memory-side 128B RMWs (WRITE_SIZE
// 200000 KB exactly) at 370 us. Both layers use the store path.

#define AGG_G(U, t) { \
    int s_##U = __builtin_amdgcn_ds_swizzle(sl, ((t) << 5) | 0x10); \
    v[U] = hw4[(uint)s_##U*16u + (uint)p]; }

#define AGG_ACC(U, t) { \
    float mk = (r + (t) < deg) ? 1.0f : 0.0f; \
    ax0 += mk*bf_lo(v[U].x); ay0 += mk*bf_hi(v[U].x); \
    ax1 += mk*bf_lo(v[U].y); ay1 += mk*bf_hi(v[U].y); \
    ax2 += mk*bf_lo(v[U].z); ay2 += mk*bf_hi(v[U].z); \
    ax3 += mk*bf_lo(v[U].w); ay3 += mk*bf_hi(v[U].w); }

template<bool RELU, bool OUT_F32>
__global__ __launch_bounds__(256, 4) void k_agg(const uint4* __restrict__ hw4,
                                                const int* __restrict__ row_start,
                                                const int* __restrict__ csr_src,
                                                const float* __restrict__ dinv,
                                                const float* __restrict__ bias,
                                                void* __restrict__ Outp){
  int wave = threadIdx.x >> 6, lane = threadIdx.x & 63;
  int p = lane & 15, q = lane >> 4;
  int node = blockIdx.x*16 + wave*4 + q;     // grid = 3125 blocks exactly

  int b0 = row_start[node], e0 = row_start[node+1];
  int deg = e0 - b0;
  int dmax = max(deg, __shfl_xor(deg, 16));  // max degree over the wave's 4 nodes
  dmax = max(dmax, __shfl_xor(dmax, 32));

  uint4 s0 = hw4[(size_t)node*16 + p];       // self loop (pre-scaled by dinv[node])
  float ax0 = bf_lo(s0.x), ay0 = bf_hi(s0.x);
  float ax1 = bf_lo(s0.y), ay1 = bf_hi(s0.y);
  float ax2 = bf_lo(s0.z), ay2 = bf_hi(s0.z);
  float ax3 = bf_lo(s0.w), ay3 = bf_hi(s0.w);

  for (int r = 0; r < dmax; r += 16){
    int t16 = r + p;
    // each group stages its own node's next 16 edge indices (replicated in group lanes)
    int sl = (t16 < deg) ? __builtin_nontemporal_load(csr_src + b0 + t16) : 0;
    {
      uint4 v[8];
      AGG_G(0,0) AGG_G(1,1) AGG_G(2,2) AGG_G(3,3)
      AGG_G(4,4) AGG_G(5,5) AGG_G(6,6) AGG_G(7,7)
      __builtin_amdgcn_sched_barrier(0);     // keep all 8 gathers in flight
      AGG_ACC(0,0) AGG_ACC(1,1) AGG_ACC(2,2) AGG_ACC(3,3)
      AGG_ACC(4,4) AGG_ACC(5,5) AGG_ACC(6,6) AGG_ACC(7,7)
    }
    if (r + 8 < dmax){                       // wave-uniform (dmax uniform)
      uint4 v[8];
      AGG_G(0,8)  AGG_G(1,9)  AGG_G(2,10) AGG_G(3,11)
      AGG_G(4,12) AGG_G(5,13) AGG_G(6,14) AGG_G(7,15)
      __builtin_amdgcn_sched_barrier(0);
      AGG_ACC(0,8)  AGG_ACC(1,9)  AGG_ACC(2,10) AGG_ACC(3,11)
      AGG_ACC(4,12) AGG_ACC(5,13) AGG_ACC(6,14) AGG_ACC(7,15)
    }
  }

  float dd = dinv[node];
  const float4* b4 = (const float4*)bias;
  float4 bA = b4[2*p], bB = b4[2*p + 1];     // bias cols [8p..8p+7]
  float vx0 = ax0*dd + bA.x, vy0 = ay0*dd + bA.y;
  float vx1 = ax1*dd + bA.z, vy1 = ay1*dd + bA.w;
  float vx2 = ax2*dd + bB.x, vy2 = ay2*dd + bB.y;
  float vx3 = ax3*dd + bB.z, vy3 = ay3*dd + bB.w;
  if (RELU){
    vx0 = fmaxf(vx0, 0.f); vy0 = fmaxf(vy0, 0.f);
    vx1 = fmaxf(vx1, 0.f); vy1 = fmaxf(vy1, 0.f);
    vx2 = fmaxf(vx2, 0.f); vy2 = fmaxf(vy2, 0.f);
    vx3 = fmaxf(vx3, 0.f); vy3 = fmaxf(vy3, 0.f);
  }

  if (OUT_F32){
    float4* Of = (float4*)Outp;              // row = 32 float4; lane p -> 2p, 2p+1
    Of[(size_t)node*32 + 2*p]     = make_float4(vx0, vy0, vx1, vy1);
    Of[(size_t)node*32 + 2*p + 1] = make_float4(vx2, vy2, vx3, vy3);
  } else {
    uint4 pk;
    pk.x = (uint)f2bf(vx0) | ((uint)f2bf(vy0) << 16);
    pk.y = (uint)f2bf(vx1) | ((uint)f2bf(vy1) << 16);
    pk.z = (uint)f2bf(vx2) | ((uint)f2bf(vy2) << 16);
    pk.w = (uint)f2bf(vx3) | ((uint)f2bf(vy3) << 16);
    ((uint4*)Outp)[(size_t)node*16 + p] = pk; // bf16 row layout for next GEMM
  }
}

// ---------------- pool + head ----------------

__global__ void k_ranges(const int* __restrict__ batch, int* __restrict__ gstart, int N, int G){
  int b = blockIdx.x*blockDim.x + threadIdx.x;
  if (b > G) return;
  int lo = 0, hi = N;
  while (lo < hi){ int mid = (lo + hi) >> 1; if (batch[mid] < b) lo = mid + 1; else hi = mid; }
  gstart[b] = lo;
}

// 8 slices per graph; one f32 atomicAdd per col per slice (128*8*128 = 131k atomics total)
__global__ void k_pool(const float* __restrict__ h3, const int* __restrict__ gstart,
                       float* __restrict__ g){
  int j = blockIdx.x, t = threadIdx.x;     // 1024 blocks x 128 threads
  int b = j >> 3, s = j & 7;
  int lo = gstart[b], hi = gstart[b+1];
  int n0 = lo + (int)(((long long)(hi - lo) * s) >> 3);
  int n1 = lo + (int)(((long long)(hi - lo) * (s + 1)) >> 3);
  float a0 = 0.f, a1 = 0.f, a2 = 0.f, a3 = 0.f;
  int n = n0;
  for (; n + 4 <= n1; n += 4){
    a0 += h3[(size_t)(n+0)*HID + t];
    a1 += h3[(size_t)(n+1)*HID + t];
    a2 += h3[(size_t)(n+2)*HID + t];
    a3 += h3[(size_t)(n+3)*HID + t];
  }
  for (; n < n1; ++n) a0 += h3[(size_t)n*HID + t];
  float cnt = (float)(hi - lo);
  float sum = (a0 + a1) + (a2 + a3);
  if (n1 > n0) atomicAdd(&g[b*HID + t], sum / fmaxf(cnt, 1.0f));
}

__global__ void k_head(const float* __restrict__ g, const float* __restrict__ W1,
                       const float* __restrict__ b1, const float* __restrict__ W2,
                       const float* __restrict__ b2, float* __restrict__ out){
  __shared__ float row[128];
  __shared__ float z[128];
  int b = blockIdx.x, t = threadIdx.x;
  row[t] = g[b*HID + t];
  __syncthreads();
  float a = b1[t];
  #pragma unroll 8
  for (int k = 0; k < 128; k++) a += row[k] * W1[k*128 + t];
  z[t] = fmaxf(a, 0.f);
  __syncthreads();
  if (t < 3){
    float o = b2[t];
    #pragma unroll 8
    for (int k = 0; k < 128; k++) o += z[k] * W2[k*3 + t];
    out[b*3 + t] = o;
  }
}

// ---------------- launch ----------------

extern "C" void kernel_launch(void* const* d_in, const int* in_sizes, int n_in,
                              void* d_out, int out_size, void* d_ws, size_t ws_size,
                              hipStream_t stream) {
  const float* x     = (const float*)d_in[0];
  const int*   ei    = (const int*)  d_in[1];
  const int*   batch = (const int*)  d_in[2];
  const float* W_emb = (const float*)d_in[3];
  const float* b_emb = (const float*)d_in[4];
  const float* W_c1  = (const float*)d_in[5];
  const float* b_c1  = (const float*)d_in[6];
  const float* W_c2  = (const float*)d_in[7];
  const float* b_c2  = (const float*)d_in[8];
  const float* W_l1  = (const float*)d_in[9];
  const float* b_l1  = (const float*)d_in[10];
  const float* W_l2  = (const float*)d_in[11];
  const float* b_l2  = (const float*)d_in[12];
  const int* src = ei;
  const int* dst = ei + N_EDGES;
  float* out = (float*)d_out;

  char* ws = (char*)d_ws;
  size_t off = 0;
  auto alloc = [&](size_t n) -> char* {
    off = (off + 255) & ~(size_t)255;
    char* p = ws + off; off += n; return p;
  };
  int*    deg       = (int*)   alloc((size_t)N_NODES*4);
  int*    cursor    = (int*)   alloc((size_t)N_NODES*4);
  int*    row_start = (int*)   alloc((size_t)(N_NODES+1)*4);
  float*  dinv      = (float*) alloc((size_t)N_NODES*4);
  int*    lexc      = (int*)   alloc((size_t)N_NODES*4);
  int*    bsum      = (int*)   alloc((size_t)SCAN_NB*4);
  int*    boff      = (int*)   alloc((size_t)SCAN_NB*4);
  int*    csr_src   = (int*)   alloc((size_t)N_EDGES*4);
  ushort* wt_emb    = (ushort*)alloc((size_t)768*HID*2);
  ushort* wt_c1     = (ushort*)alloc((size_t)HID*HID*2);
  ushort* wt_c2     = (ushort*)alloc((size_t)HID*HID*2);
  // t1 (bf16, 12.8 MB) and h3f (f32, 25.6 MB) are live at disjoint times -> alias
  char*   big       =          alloc((size_t)N_NODES*HID*4);
  ushort* t1        = (ushort*)big;
  float*  h3f       = (float*) big;
  ushort* h2        = (ushort*)alloc((size_t)N_NODES*HID*2);
  uint*   hw        = (uint*)  alloc((size_t)N_NODES*64*4);   // packed bf16 x2, row layout
  float*  g         = (float*) alloc((size_t)N_GRAPHS*HID*4);
  int*    gstart    = (int*)   alloc((size_t)(N_GRAPHS+1)*4);

  hipMemsetAsync(deg,    0, (size_t)N_NODES*4, stream);
  hipMemsetAsync(cursor, 0, (size_t)N_NODES*4, stream);
  hipMemsetAsync(g,      0, (size_t)N_GRAPHS*HID*4, stream);

  int eb = (N_EDGES + 255) / 256;
  int nb = (N_NODES + 255) / 256;
  k_count  <<<eb, 256, 0, stream>>>(dst, deg, N_EDGES);
  k_scan1  <<<SCAN_NB, SCAN_BS, 0, stream>>>(deg, lexc, bsum, dinv, N_NODES);
  k_scan2  <<<1, 256, 0, stream>>>(bsum, boff, row_start);
  k_scan3  <<<nb, 256, 0, stream>>>(lexc, boff, row_start, N_NODES);
  k_scatter<<<eb, 256, 0, stream>>>(src, dst, row_start, cursor, csr_src, N_EDGES);
  k_ranges <<<1, 256, 0, stream>>>(batch, gstart, N_NODES, N_GRAPHS);

  k_wt3<<<(768*HID + 2*HID*HID + 255)/256, 256, 0, stream>>>(W_emb, wt_emb, W_c1, wt_c1, W_c2, wt_c2);

  int gemm_blocks = (N_NODES + 63) / 64;
  int agg_blocks  = N_NODES / 16;           // 3125, 16 nodes per block
  // t1 = x @ W_emb + b_emb (bf16)
  k_gemm<768, true,  true,  true,  false><<<gemm_blocks, 256, 0, stream>>>(x,  wt_emb, b_emb, nullptr, t1, N_NODES);
  // hw = (t1 @ W_c1) * dinv[row]  (packed bf16)
  k_gemm<128, false, true,  false, true ><<<gemm_blocks, 256, 0, stream>>>(t1, wt_c1, nullptr, dinv, hw, N_NODES);
  // h2 = relu(agg(hw) + b_c1) (bf16)
  k_agg<true,  false><<<agg_blocks, 256, 0, stream>>>((const uint4*)hw, row_start, csr_src, dinv, b_c1, h2);
  // hw = (h2 @ W_c2) * dinv[row] (packed bf16)
  k_gemm<128, false, true,  false, true ><<<gemm_blocks, 256, 0, stream>>>(h2, wt_c2, nullptr, dinv, hw, N_NODES);
  // h3f = agg(hw) + b_c2  (f32, overwrites dead t1)
  k_agg<false, true ><<<agg_blocks, 256, 0, stream>>>((const uint4*)hw, row_start, csr_src, dinv, b_c2, h3f);
  // g = pooled(h3f)
  k_pool<<<N_GRAPHS*8, 128, 0, stream>>>(h3f, gstart, g);

  k_head<<<N_GRAPHS, 128, 0, stream>>>(g, W_l1, b_l1, W_l2, b_l2, out);
}

// Round 6
// 447.398 us; speedup vs baseline: 1.7278x; 1.0482x over previous
//
#include <hip/hip_runtime.h>
#include <hip/hip_bf16.h>

#define N_NODES  50000
#define N_GRAPHS 128
#define N_EDGES  800000
#define HID      128
#define SCAN_BS  256
#define SCAN_NB  ((N_NODES + SCAN_BS - 1) / SCAN_BS)

typedef __attribute__((ext_vector_type(8))) short short8;
typedef __attribute__((ext_vector_type(4))) float f32x4;

static __device__ __forceinline__ ushort f2bf(float f){
  __hip_bfloat16 h = __float2bfloat16(f);
  return *reinterpret_cast<ushort*>(&h);
}
static __device__ __forceinline__ float bf_lo(uint pk){ return __uint_as_float(pk << 16); }
static __device__ __forceinline__ float bf_hi(uint pk){ return __uint_as_float(pk & 0xffff0000u); }

// ---------------- fused setup: edge count + weight transpose/convert + ranges + zero g ----
// All jobs independent; branch on blockIdx. Grid = 3125 (count needs all blocks).

__global__ void k_setup(const int* __restrict__ dst, int* __restrict__ deg,
                        const int* __restrict__ batch, int* __restrict__ gstart,
                        float* __restrict__ g,
                        const float* __restrict__ W0, ushort* __restrict__ T0,
                        const float* __restrict__ W1, ushort* __restrict__ T1){
  int bid = blockIdx.x, t = threadIdx.x;
  int i = bid*256 + t;
  if (i < N_EDGES) atomicAdd(&deg[dst[i]], 1);
  if (bid == 0){
    int b = t;
    if (b <= N_GRAPHS){
      int lo = 0, hi = N_NODES;
      while (lo < hi){ int mid = (lo + hi) >> 1; if (batch[mid] < b) lo = mid + 1; else hi = mid; }
      gstart[b] = lo;
    }
  } else if (bid == 1){
    for (int j = t; j < N_GRAPHS*HID; j += 256) g[j] = 0.f;
  } else if (bid < 2 + 384){                       // W_emb: 768*128 = 384 blocks
    int idx = (bid - 2)*256 + t;
    int k = idx >> 7, n = idx & 127;
    T0[n*768 + k] = f2bf(W0[idx]);
  } else if (bid < 2 + 384 + 64){                  // W_c1: 128*128 = 64 blocks
    int idx = (bid - 2 - 384)*256 + t;
    int k = idx >> 7, n = idx & 127;
    T1[n*HID + k] = f2bf(W1[idx]);
  }
}

// ---------------- prefix-sum chain for CSR ----------------

__global__ void k_scan1(const int* __restrict__ deg, int* __restrict__ lexc,
                        int* __restrict__ bsum, float* __restrict__ dinv, int N){
  __shared__ int s[SCAN_BS];
  int t = threadIdx.x, i = blockIdx.x*SCAN_BS + t;
  int v = (i < N) ? deg[i] : 0;
  if (i < N) dinv[i] = rsqrtf((float)(v + 1));   // +1 self loop
  s[t] = v;
  __syncthreads();
  int acc = v;
  for (int d = 1; d < SCAN_BS; d <<= 1){
    int u = (t >= d) ? s[t-d] : 0;
    __syncthreads();
    acc += u; s[t] = acc;
    __syncthreads();
  }
  if (i < N) lexc[i] = acc - v;
  if (t == SCAN_BS-1) bsum[blockIdx.x] = acc;
}

__global__ void k_scan2(const int* __restrict__ bsum, int* __restrict__ boff,
                        int* __restrict__ row_start){
  __shared__ int s[SCAN_NB];
  int t = threadIdx.x;
  int v = (t < SCAN_NB) ? bsum[t] : 0;
  if (t < SCAN_NB) s[t] = v;
  __syncthreads();
  int acc = v;
  for (int d = 1; d < SCAN_NB; d <<= 1){
    int u = (t >= d && t - d < SCAN_NB) ? s[t-d] : 0;
    __syncthreads();
    if (t < SCAN_NB){ acc += u; s[t] = acc; }
    __syncthreads();
  }
  if (t < SCAN_NB) boff[t] = acc - v;
  if (t == SCAN_NB-1) row_start[N_NODES] = acc;
}

__global__ void k_scan3(const int* __restrict__ lexc, const int* __restrict__ boff,
                        int* __restrict__ row_start, int N){
  int i = blockIdx.x*blockDim.x + threadIdx.x;
  if (i < N) row_start[i] = lexc[i] + boff[i >> 8];
}

__global__ void k_scatter(const int* __restrict__ src, const int* __restrict__ dst,
                          const int* __restrict__ row_start, int* __restrict__ cursor,
                          int* __restrict__ csr_src, int E){
  int i = blockIdx.x*blockDim.x + threadIdx.x;
  if (i >= E) return;
  int d = dst[i];
  int pos = row_start[d] + atomicAdd(&cursor[d], 1);
  csr_src[pos] = src[i];
}

// ---------------- bf16 MFMA GEMM: Out[M][128] = A[M][K] @ W[K][128] ----------------

template<int K, bool A_F32, bool OUT_BF16, bool BIAS, bool RELU, bool SCALE>
__global__ __launch_bounds__(256) void k_gemm(const void* __restrict__ Aptr,
                                              const ushort* __restrict__ Wt,
                                              const float* __restrict__ bias,
                                              const float* __restrict__ rowscale,
                                              void* __restrict__ Outp, int M){
  __shared__ __align__(16) ushort lA[64*32];    // [row][k]
  __shared__ __align__(16) ushort lB[128*32];   // [n][k]
  int tid  = threadIdx.x;
  int wave = tid >> 6, lane = tid & 63;
  int kg   = lane >> 4, lr = lane & 15;
  int m0   = blockIdx.x * 64;

  f32x4 acc[8];
  #pragma unroll
  for (int i = 0; i < 8; i++) acc[i] = f32x4{0.f, 0.f, 0.f, 0.f};

  for (int k0 = 0; k0 < K; k0 += 32){
    if (A_F32){
      const float* A = (const float*)Aptr;
      #pragma unroll
      for (int i = 0; i < 2; i++){
        int l = tid + i*256;
        int r = l >> 3, c4 = (l & 7) * 4;
        int gm = m0 + r;
        float4 v = make_float4(0.f, 0.f, 0.f, 0.f);
        if (gm < M) v = *(const float4*)(A + (size_t)gm*K + k0 + c4);
        ushort4 u; u.x = f2bf(v.x); u.y = f2bf(v.y); u.z = f2bf(v.z); u.w = f2bf(v.w);
        *(ushort4*)&lA[r*32 + c4] = u;
      }
    } else {
      const ushort* A = (const ushort*)Aptr;
      int r = tid >> 2, c8 = (tid & 3) * 8;
      int gm = m0 + r;
      int4 v = make_int4(0, 0, 0, 0);
      if (gm < M) v = *(const int4*)(A + (size_t)gm*K + k0 + c8);
      *(int4*)&lA[r*32 + c8] = v;
    }
    #pragma unroll
    for (int i = 0; i < 2; i++){
      int l = tid + i*256;
      int n = l >> 2, c8 = (l & 3) * 8;
      *(int4*)&lB[n*32 + c8] = *(const int4*)(Wt + (size_t)n*K + k0 + c8);
    }
    __syncthreads();

    short8 a = *(const short8*)&lA[(wave*16 + lr)*32 + kg*8];
    #pragma unroll
    for (int nt = 0; nt < 8; nt++){
      short8 b = *(const short8*)&lB[(nt*16 + lr)*32 + kg*8];
      acc[nt] = __builtin_amdgcn_mfma_f32_16x16x32_bf16(a, b, acc[nt], 0, 0, 0);
    }
    __syncthreads();
  }

  #pragma unroll
  for (int nt = 0; nt < 8; nt++){
    #pragma unroll
    for (int r = 0; r < 4; r++){
      int gm = m0 + wave*16 + kg*4 + r;
      int n  = nt*16 + lr;
      if (gm < M){
        float v = acc[nt][r];
        if (BIAS)  v += bias[n];
        if (RELU)  v = fmaxf(v, 0.f);
        if (SCALE) v *= rowscale[gm];
        if (OUT_BF16) ((ushort*)Outp)[(size_t)gm*HID + n] = f2bf(v);
        else          ((float*)Outp)[(size_t)gm*HID + n] = v;
      }
    }
  }
}

// ---------------- edge aggregation (dwordx4 gathers, 4 edges/instruction) ----------------
// out[d] = dinv[d] * (sum_{s in N(d)} in[s] + in[d]);  `in` rows are pre-scaled by
// dinv[s] (GCN symmetric norm commuted past the weight matmul: agg(hW) = agg(h)W,
// so NO bias / relu here — they live in the downstream GEMM / head).
// Wave = 4 nodes; group q (16 lanes) owns node q; lane p loads uint4 = row bytes
// [p*16, p*16+16) -> one wave instruction gathers 4 edges' FULL 256B rows (1 KB,
// zero overfetch). Per 16-edge stage: two 8-deep bursts; sched_barrier(0) keeps
// all 8 gathers in flight (round-4 lesson: compiler otherwise interleaves
// load->use, killing MLP). Edge index broadcast within a group via ds_swizzle
// BitMode src=(lane&0x10)|t. Masked slots gather row 0 (cache-hot), contribution
// zeroed via mask-FMA. Pool NOT fused (round-4: scattered atomics = 1.6M
// memory-side RMWs, 370 us).

#define AGG_G(U, t) { \
    int s_##U = __builtin_amdgcn_ds_swizzle(sl, ((t) << 5) | 0x10); \
    v[U] = hw4[(uint)s_##U*16u + (uint)p]; }

#define AGG_ACC(U, t) { \
    float mk = (r + (t) < deg) ? 1.0f : 0.0f; \
    ax0 += mk*bf_lo(v[U].x); ay0 += mk*bf_hi(v[U].x); \
    ax1 += mk*bf_lo(v[U].y); ay1 += mk*bf_hi(v[U].y); \
    ax2 += mk*bf_lo(v[U].z); ay2 += mk*bf_hi(v[U].z); \
    ax3 += mk*bf_lo(v[U].w); ay3 += mk*bf_hi(v[U].w); }

template<bool OUT_F32>
__global__ __launch_bounds__(256, 4) void k_agg(const uint4* __restrict__ hw4,
                                                const int* __restrict__ row_start,
                                                const int* __restrict__ csr_src,
                                                const float* __restrict__ dinv,
                                                void* __restrict__ Outp){
  int wave = threadIdx.x >> 6, lane = threadIdx.x & 63;
  int p = lane & 15, q = lane >> 4;
  int node = blockIdx.x*16 + wave*4 + q;     // grid = 3125 blocks exactly

  int b0 = row_start[node], e0 = row_start[node+1];
  int deg = e0 - b0;
  int dmax = max(deg, __shfl_xor(deg, 16));  // max degree over the wave's 4 nodes
  dmax = max(dmax, __shfl_xor(dmax, 32));

  uint4 s0 = hw4[(size_t)node*16 + p];       // self loop (row pre-scaled by dinv[node])
  float ax0 = bf_lo(s0.x), ay0 = bf_hi(s0.x);
  float ax1 = bf_lo(s0.y), ay1 = bf_hi(s0.y);
  float ax2 = bf_lo(s0.z), ay2 = bf_hi(s0.z);
  float ax3 = bf_lo(s0.w), ay3 = bf_hi(s0.w);

  for (int r = 0; r < dmax; r += 16){
    int t16 = r + p;
    // each group stages its own node's next 16 edge indices (replicated in group lanes)
    int sl = (t16 < deg) ? __builtin_nontemporal_load(csr_src + b0 + t16) : 0;
    {
      uint4 v[8];
      AGG_G(0,0) AGG_G(1,1) AGG_G(2,2) AGG_G(3,3)
      AGG_G(4,4) AGG_G(5,5) AGG_G(6,6) AGG_G(7,7)
      __builtin_amdgcn_sched_barrier(0);     // keep all 8 gathers in flight
      AGG_ACC(0,0) AGG_ACC(1,1) AGG_ACC(2,2) AGG_ACC(3,3)
      AGG_ACC(4,4) AGG_ACC(5,5) AGG_ACC(6,6) AGG_ACC(7,7)
    }
    if (r + 8 < dmax){                       // wave-uniform (dmax uniform)
      uint4 v[8];
      AGG_G(0,8)  AGG_G(1,9)  AGG_G(2,10) AGG_G(3,11)
      AGG_G(4,12) AGG_G(5,13) AGG_G(6,14) AGG_G(7,15)
      __builtin_amdgcn_sched_barrier(0);
      AGG_ACC(0,8)  AGG_ACC(1,9)  AGG_ACC(2,10) AGG_ACC(3,11)
      AGG_ACC(4,12) AGG_ACC(5,13) AGG_ACC(6,14) AGG_ACC(7,15)
    }
  }

  float dd = dinv[node];
  float vx0 = ax0*dd, vy0 = ay0*dd;
  float vx1 = ax1*dd, vy1 = ay1*dd;
  float vx2 = ax2*dd, vy2 = ay2*dd;
  float vx3 = ax3*dd, vy3 = ay3*dd;

  if (OUT_F32){
    float4* Of = (float4*)Outp;              // row = 32 float4; lane p -> 2p, 2p+1
    Of[(size_t)node*32 + 2*p]     = make_float4(vx0, vy0, vx1, vy1);
    Of[(size_t)node*32 + 2*p + 1] = make_float4(vx2, vy2, vx3, vy3);
  } else {
    uint4 pk;
    pk.x = (uint)f2bf(vx0) | ((uint)f2bf(vy0) << 16);
    pk.y = (uint)f2bf(vx1) | ((uint)f2bf(vy1) << 16);
    pk.z = (uint)f2bf(vx2) | ((uint)f2bf(vy2) << 16);
    pk.w = (uint)f2bf(vx3) | ((uint)f2bf(vy3) << 16);
    ((uint4*)Outp)[(size_t)node*16 + p] = pk; // bf16 row layout for next GEMM
  }
}

// ---------------- pool + head ----------------

// 8 slices per graph; one f32 atomicAdd per col per slice (128*8*128 = 131k atomics total)
__global__ void k_pool(const float* __restrict__ a2, const int* __restrict__ gstart,
                       float* __restrict__ g){
  int j = blockIdx.x, t = threadIdx.x;     // 1024 blocks x 128 threads
  int b = j >> 3, s = j & 7;
  int lo = gstart[b], hi = gstart[b+1];
  int n0 = lo + (int)(((long long)(hi - lo) * s) >> 3);
  int n1 = lo + (int)(((long long)(hi - lo) * (s + 1)) >> 3);
  float a0 = 0.f, a1 = 0.f, aa2 = 0.f, a3 = 0.f;
  int n = n0;
  for (; n + 4 <= n1; n += 4){
    a0  += a2[(size_t)(n+0)*HID + t];
    a1  += a2[(size_t)(n+1)*HID + t];
    aa2 += a2[(size_t)(n+2)*HID + t];
    a3  += a2[(size_t)(n+3)*HID + t];
  }
  for (; n < n1; ++n) a0 += a2[(size_t)n*HID + t];
  float cnt = (float)(hi - lo);
  float sum = (a0 + a1) + (aa2 + a3);
  if (n1 > n0) atomicAdd(&g[b*HID + t], sum / fmaxf(cnt, 1.0f));
}

// head now includes the commuted W_c2 layer: h3g = gg@W_c2 + b_c2 (128x128x128, trivial)
__global__ void k_head(const float* __restrict__ g,
                       const float* __restrict__ Wc2, const float* __restrict__ bc2,
                       const float* __restrict__ W1, const float* __restrict__ b1,
                       const float* __restrict__ W2, const float* __restrict__ b2,
                       float* __restrict__ out){
  __shared__ float gg[128];
  __shared__ float r1[128];
  __shared__ float z[128];
  int b = blockIdx.x, t = threadIdx.x;
  gg[t] = g[b*HID + t];
  __syncthreads();
  float a = bc2[t];
  #pragma unroll 8
  for (int k = 0; k < 128; k++) a += gg[k] * Wc2[k*128 + t];
  r1[t] = a;                                 // second conv output (no relu)
  __syncthreads();
  float c = b1[t];
  #pragma unroll 8
  for (int k = 0; k < 128; k++) c += r1[k] * W1[k*128 + t];
  z[t] = fmaxf(c, 0.f);
  __syncthreads();
  if (t < 3){
    float o = b2[t];
    #pragma unroll 8
    for (int k = 0; k < 128; k++) o += z[k] * W2[k*3 + t];
    out[b*3 + t] = o;
  }
}

// ---------------- launch ----------------
// Algebra: agg(hW) = agg(h)W and pool is linear, so:
//   t1s = dinv .* (x@W_emb + b_emb)                 [bf16, GEMM epilogue fold]
//   a1  = dinv .* (A+I)-sum of t1s                  [bf16, k_agg]
//   h2s = dinv .* relu(a1@W_c1 + b_c1)              [bf16, GEMM epilogue fold]
//   a2  = dinv .* (A+I)-sum of h2s                  [f32,  k_agg]
//   gg  = segment-mean(a2)                          [k_pool]
//   out = head(gg@W_c2 + b_c2)                      [k_head, W_c2 GEMM now 128 rows]
// -> second conv's 50000-row GEMM eliminated.

extern "C" void kernel_launch(void* const* d_in, const int* in_sizes, int n_in,
                              void* d_out, int out_size, void* d_ws, size_t ws_size,
                              hipStream_t stream) {
  const float* x     = (const float*)d_in[0];
  const int*   ei    = (const int*)  d_in[1];
  const int*   batch = (const int*)  d_in[2];
  const float* W_emb = (const float*)d_in[3];
  const float* b_emb = (const float*)d_in[4];
  const float* W_c1  = (const float*)d_in[5];
  const float* b_c1  = (const float*)d_in[6];
  const float* W_c2  = (const float*)d_in[7];
  const float* b_c2  = (const float*)d_in[8];
  const float* W_l1  = (const float*)d_in[9];
  const float* b_l1  = (const float*)d_in[10];
  const float* W_l2  = (const float*)d_in[11];
  const float* b_l2  = (const float*)d_in[12];
  const int* src = ei;
  const int* dst = ei + N_EDGES;
  float* out = (float*)d_out;

  char* ws = (char*)d_ws;
  size_t off = 0;
  auto alloc = [&](size_t n) -> char* {
    off = (off + 255) & ~(size_t)255;
    char* p = ws + off; off += n; return p;
  };
  int*    deg       = (int*)   alloc((size_t)N_NODES*8);      // deg + cursor, one memset
  int*    cursor    = deg + N_NODES;
  int*    row_start = (int*)   alloc((size_t)(N_NODES+1)*4);
  float*  dinv      = (float*) alloc((size_t)N_NODES*4);
  int*    lexc      = (int*)   alloc((size_t)N_NODES*4);
  int*    bsum      = (int*)   alloc((size_t)SCAN_NB*4);
  int*    boff      = (int*)   alloc((size_t)SCAN_NB*4);
  int*    csr_src   = (int*)   alloc((size_t)N_EDGES*4);
  ushort* wt_emb    = (ushort*)alloc((size_t)768*HID*2);
  ushort* wt_c1     = (ushort*)alloc((size_t)HID*HID*2);
  // t1s (bf16, 12.8 MB) dead after agg1; a2 (f32, 25.6 MB) written later -> alias
  char*   big       =          alloc((size_t)N_NODES*HID*4);
  ushort* t1s       = (ushort*)big;
  float*  a2        = (float*) big;
  ushort* a1        = (ushort*)alloc((size_t)N_NODES*HID*2);
  ushort* h2s       = (ushort*)alloc((size_t)N_NODES*HID*2);
  float*  g         = (float*) alloc((size_t)N_GRAPHS*HID*4);
  int*    gstart    = (int*)   alloc((size_t)(N_GRAPHS+1)*4);

  hipMemsetAsync(deg, 0, (size_t)N_NODES*8, stream);

  int eb = (N_EDGES + 255) / 256;           // 3125
  int nb = (N_NODES + 255) / 256;
  k_setup  <<<eb, 256, 0, stream>>>(dst, deg, batch, gstart, g, W_emb, wt_emb, W_c1, wt_c1);
  k_scan1  <<<SCAN_NB, SCAN_BS, 0, stream>>>(deg, lexc, bsum, dinv, N_NODES);
  k_scan2  <<<1, 256, 0, stream>>>(bsum, boff, row_start);
  k_scan3  <<<nb, 256, 0, stream>>>(lexc, boff, row_start, N_NODES);
  k_scatter<<<eb, 256, 0, stream>>>(src, dst, row_start, cursor, csr_src, N_EDGES);

  int gemm_blocks = (N_NODES + 63) / 64;
  int agg_blocks  = N_NODES / 16;           // 3125, 16 nodes per block
  // t1s = dinv .* (x @ W_emb + b_emb)   (bf16)
  k_gemm<768, true,  true, true, false, true><<<gemm_blocks, 256, 0, stream>>>(x, wt_emb, b_emb, dinv, t1s, N_NODES);
  // a1 = dinv .* agg(t1s)               (bf16)
  k_agg<false><<<agg_blocks, 256, 0, stream>>>((const uint4*)t1s, row_start, csr_src, dinv, a1);
  // h2s = dinv .* relu(a1 @ W_c1 + b_c1)  (bf16)
  k_gemm<128, false, true, true, true,  true><<<gemm_blocks, 256, 0, stream>>>(a1, wt_c1, b_c1, dinv, h2s, N_NODES);
  // a2 = dinv .* agg(h2s)               (f32, overwrites dead t1s)
  k_agg<true ><<<agg_blocks, 256, 0, stream>>>((const uint4*)h2s, row_start, csr_src, dinv, a2);
  // gg = segment-mean(a2)
  k_pool<<<N_GRAPHS*8, 128, 0, stream>>>(a2, gstart, g);
  // out = head(gg@W_c2 + b_c2)
  k_head<<<N_GRAPHS, 128, 0, stream>>>(g, W_c2, b_c2, W_l1, b_l1, W_l2, b_l2, out);
}